// Round 9
// baseline (388.494 us; speedup 1.0000x reference)
//
#include <hip/hip_runtime.h>
#include <hip/hip_bf16.h>
#include <cstddef>

#define NN 100000
#define NE 1600000
#define NG 2000
#define NS 40
#define INF 64
#define F 128
#define FFN_DIM 1024
#define NB 782            // ceil(100000/128) buckets of 128 nodes
#define BCAP 3072         // fixed bucket capacity (mean 2048, sigma 45 -> 19+ sigma margin)
#define SC_BLOCKS 512
#define SC_CHUNK 3125     // 512*3125 = 1.6M edges exactly

using bf16 = __hip_bfloat16;
typedef __attribute__((ext_vector_type(8))) short short8;
typedef __attribute__((ext_vector_type(4))) float f32x4;
typedef __attribute__((ext_vector_type(2))) float f32x2;

__device__ __forceinline__ short f2bs(float f){
    union { bf16 b; short s; } u; u.b = __float2bfloat16(f); return u.s;
}
__device__ __forceinline__ unsigned int pk2(float a, float b){
    return (unsigned int)(unsigned short)f2bs(a) | ((unsigned int)(unsigned short)f2bs(b) << 16);
}

// ---------------- init: bucket cursors + Wg_top^T bf16 convert (fused, 1 block) ----------------
__global__ __launch_bounds__(1024) void k_init(int* __restrict__ bcursor, const float* __restrict__ Wg,
                                               unsigned short* __restrict__ Wgb){
    int t = threadIdx.x;
    if (t < NB) bcursor[t] = t * BCAP;
    for (int i=t; i<16384; i+=1024){
        int k = i >> 7, n = i & 127;
        Wgb[n*128 + k] = (unsigned short)f2bs(Wg[(size_t)k*F + n]);
    }
}

// ---------------- xws = (x @ W_gcn) * dinv[row], bf16 MFMA, stored fp8 e4m3 ----------------
__global__ __launch_bounds__(256) void k_xws(const float* __restrict__ x, const float* __restrict__ W,
                                             const float* __restrict__ dinv, unsigned char* __restrict__ xws8){
    __shared__ short Xs[128*72];   // [row][k], stride 72 (K=64)
    __shared__ short Ws[128*72];   // [feature][k], stride 72
    int t = threadIdx.x;
    int rowBase = blockIdx.x * 128;
    #pragma unroll
    for (int i=0;i<32;i++){
        int id = i*256+t; int k = id>>7, n = id&127;
        Ws[n*72 + k] = f2bs(W[id]);
    }
    #pragma unroll
    for (int i=0;i<8;i++){
        int id = i*256+t;              // 2048 float4 slots
        int r = id>>4; int k4 = (id&15)*4;
        int row = rowBase + r; if (row >= NN) row = NN-1;
        float4 v = *(const float4*)&x[(size_t)row*INF + k4];
        *(unsigned int*)&Xs[r*72 + k4]     = pk2(v.x, v.y);
        *(unsigned int*)&Xs[r*72 + k4 + 2] = pk2(v.z, v.w);
    }
    __syncthreads();
    int lane = t & 63, w = t >> 6;
    int lr = lane & 15, quad = lane >> 4;
    f32x4 acc[2][8];
    #pragma unroll
    for (int i=0;i<2;i++)
        #pragma unroll
        for (int j=0;j<8;j++) acc[i][j] = (f32x4){0.f,0.f,0.f,0.f};
    #pragma unroll
    for (int ks=0; ks<2; ++ks){
        int kb = ks*32 + quad*8;
        short8 b0 = *(const short8*)&Xs[((w  )*16 + lr)*72 + kb];
        short8 b1 = *(const short8*)&Xs[((w+4)*16 + lr)*72 + kb];
        #pragma unroll
        for (int mt=0; mt<8; ++mt){
            short8 a = *(const short8*)&Ws[(mt*16 + lr)*72 + kb];
            acc[0][mt] = __builtin_amdgcn_mfma_f32_16x16x32_bf16(a, b0, acc[0][mt], 0, 0, 0);
            acc[1][mt] = __builtin_amdgcn_mfma_f32_16x16x32_bf16(a, b1, acc[1][mt], 0, 0, 0);
        }
    }
    #pragma unroll
    for (int rt=0; rt<2; ++rt){
        int row = rowBase + (w + rt*4)*16 + lr;
        if (row < NN){
            float dv = dinv[row];
            #pragma unroll
            for (int mt=0; mt<8; ++mt){
                int p = __builtin_amdgcn_cvt_pk_fp8_f32(acc[rt][mt][0]*dv, acc[rt][mt][1]*dv, 0, false);
                p     = __builtin_amdgcn_cvt_pk_fp8_f32(acc[rt][mt][2]*dv, acc[rt][mt][3]*dv, p, true);
                *(int*)&xws8[(size_t)row*F + mt*16 + quad*4] = p;
            }
        }
    }
}

// ---------------- binned scatter: pack (row<<7|col&127) into fixed bucket regions ----------------
__global__ __launch_bounds__(1024) void k_scatter2(const int* __restrict__ ei, int* __restrict__ bcursor,
                                                   int* __restrict__ ebuf){
    __shared__ int lh[NB];
    __shared__ int lb[NB];
    int t = threadIdx.x;
    int base = blockIdx.x * SC_CHUNK;
    for (int b=t; b<NB; b+=1024) lh[b] = 0;
    __syncthreads();
    int rr[4], cc[4];
    #pragma unroll
    for (int q=0;q<4;q++){
        int i = t + q*1024;
        bool v = (i < SC_CHUNK);
        int idx = v ? (base + i) : base;
        rr[q] = ei[idx];
        cc[q] = ei[NE + idx];
        if (v) atomicAdd(&lh[cc[q]>>7], 1);
    }
    __syncthreads();
    for (int b=t; b<NB; b+=1024){
        int n = lh[b];
        lb[b] = n ? atomicAdd(&bcursor[b], n) : 0;
        lh[b] = 0;
    }
    __syncthreads();
    #pragma unroll
    for (int q=0;q<4;q++){
        int i = t + q*1024;
        if (i < SC_CHUNK){
            int b = cc[q] >> 7;
            int rk = atomicAdd(&lh[b], 1);
            ebuf[lb[b] + rk] = (rr[q] << 7) | (cc[q] & 127);
        }
    }
}

// ---------------- per-bucket counting sort; LDS-staged output (coalesced ebuf2 writes) ----------------
__global__ __launch_bounds__(256) void k_sort(const int* __restrict__ ebuf, const int* __restrict__ bcursor,
                                              int* __restrict__ cnt, float* __restrict__ dinv,
                                              int* __restrict__ nstart, int* __restrict__ ebuf2){
    __shared__ int lh[128];
    __shared__ int s[128];
    __shared__ int lcur[128];
    __shared__ int sorted[BCAP];
    int t = threadIdx.x;
    int b = blockIdx.x;
    int e0 = b * BCAP;
    int nE = bcursor[b] - e0;
    if (t < 128) lh[t] = 0;
    __syncthreads();
    for (int i=t; i<nE; i+=256) atomicAdd(&lh[ebuf[e0+i] & 127], 1);
    __syncthreads();
    int c = (t < 128) ? lh[t] : 0;
    if (t < 128) s[t] = c;
    __syncthreads();
    #pragma unroll
    for (int off=1; off<128; off<<=1){
        int v = (t >= off && t < 128) ? s[t-off] : 0;
        __syncthreads();
        if (t < 128) s[t] += v;
        __syncthreads();
    }
    int node = b*128 + t;
    if (t < 128){
        int excl = s[t] - c;
        lcur[t] = excl;
        if (node < NN){
            nstart[node] = e0 + excl;
            cnt[node] = c;
            dinv[node] = rsqrtf((float)c + 2.0f);
        }
    }
    __syncthreads();
    // scatter into LDS by rank, then stream out coalesced
    for (int i=t; i<nE; i+=256){
        int v = ebuf[e0 + i];
        int nl = v & 127;
        int rk = atomicAdd(&lcur[nl], 1);
        sorted[rk] = (v >> 7) << 5;   // row * 32 (uint-word offset into xws8)
    }
    __syncthreads();
    for (int i=t; i<nE; i+=256) ebuf2[e0 + i] = sorted[i];
}

// ---------------- fused: CSR gather + GCN epilogue + BN + ReLU -> h,hb + pool -> z, znb ----------------
__global__ __launch_bounds__(256) void k_aggpool(const unsigned char* __restrict__ xws8,
                                                 const int* __restrict__ nstart, const int* __restrict__ cnt,
                                                 const float* __restrict__ dinv, const float* __restrict__ b_gcn,
                                                 const float* __restrict__ bn_g, const float* __restrict__ bn_b,
                                                 const int* __restrict__ ebuf2,
                                                 const float* __restrict__ lnpre_g, const float* __restrict__ lnpre_b,
                                                 float* __restrict__ h, unsigned short* __restrict__ hb,
                                                 float* __restrict__ z, unsigned short* __restrict__ znb){
    __shared__ float zacc[4][128];
    int t = threadIdx.x;
    int lane = t & 63, w = t >> 6;
    int half = lane >> 5, lh = lane & 31;
    int g = blockIdx.x;
    const unsigned int* xw32 = (const unsigned int*)xws8;   // row stride = 32 uints
    unsigned int* hb32 = (unsigned int*)hb;
    unsigned int* znb32 = (unsigned int*)znb;

    float4 bg4  = *(const float4*)&b_gcn[4*lh];
    float4 bng4 = *(const float4*)&bn_g[4*lh];
    float4 bnb4 = *(const float4*)&bn_b[4*lh];
    const float bns = rsqrtf(1.f + 1e-5f);

    float za0=0.f, za1=0.f, za2=0.f, za3=0.f;

    for (int i = w; i < 50; i += 4){
        int node = g*50 + i;
        int s0n = nstart[node]; int dg = cnt[node]; float dv = dinv[node];
        unsigned int us = xw32[node*32 + lh];   // self-loop, issued early
        float a0=0.f, a1=0.f, a2=0.f, a3=0.f;
        int j=0;
        for (; j+8<=dg; j+=8){
            int r0 = ebuf2[s0n+j+0+half];
            int r1 = ebuf2[s0n+j+2+half];
            int r2 = ebuf2[s0n+j+4+half];
            int r3 = ebuf2[s0n+j+6+half];
            unsigned int u0 = xw32[r0 + lh];
            unsigned int u1 = xw32[r1 + lh];
            unsigned int u2 = xw32[r2 + lh];
            unsigned int u3 = xw32[r3 + lh];
            f32x2 l0 = __builtin_amdgcn_cvt_pk_f32_fp8(u0, false);
            f32x2 h0 = __builtin_amdgcn_cvt_pk_f32_fp8(u0, true);
            f32x2 l1 = __builtin_amdgcn_cvt_pk_f32_fp8(u1, false);
            f32x2 h1 = __builtin_amdgcn_cvt_pk_f32_fp8(u1, true);
            f32x2 l2 = __builtin_amdgcn_cvt_pk_f32_fp8(u2, false);
            f32x2 h2 = __builtin_amdgcn_cvt_pk_f32_fp8(u2, true);
            f32x2 l3 = __builtin_amdgcn_cvt_pk_f32_fp8(u3, false);
            f32x2 h3 = __builtin_amdgcn_cvt_pk_f32_fp8(u3, true);
            a0 += (l0.x + l1.x) + (l2.x + l3.x);
            a1 += (l0.y + l1.y) + (l2.y + l3.y);
            a2 += (h0.x + h1.x) + (h2.x + h3.x);
            a3 += (h0.y + h1.y) + (h2.y + h3.y);
        }
        for (; j+2<=dg; j+=2){
            int r0 = ebuf2[s0n+j+half];
            unsigned int u0 = xw32[r0 + lh];
            f32x2 l0 = __builtin_amdgcn_cvt_pk_f32_fp8(u0, false);
            f32x2 h0 = __builtin_amdgcn_cvt_pk_f32_fp8(u0, true);
            a0 += l0.x; a1 += l0.y; a2 += h0.x; a3 += h0.y;
        }
        if (j < dg && half == 0){
            int r0 = ebuf2[s0n+j];
            unsigned int u0 = xw32[r0 + lh];
            f32x2 l0 = __builtin_amdgcn_cvt_pk_f32_fp8(u0, false);
            f32x2 h0 = __builtin_amdgcn_cvt_pk_f32_fp8(u0, true);
            a0 += l0.x; a1 += l0.y; a2 += h0.x; a3 += h0.y;
        }
        a0 += __shfl_xor(a0, 32);
        a1 += __shfl_xor(a1, 32);
        a2 += __shfl_xor(a2, 32);
        a3 += __shfl_xor(a3, 32);
        f32x2 fl = __builtin_amdgcn_cvt_pk_f32_fp8(us, false);
        f32x2 fh = __builtin_amdgcn_cvt_pk_f32_fp8(us, true);
        float p0 = dv*(a0 + 2.f*fl.x) + bg4.x;
        float p1 = dv*(a1 + 2.f*fl.y) + bg4.y;
        float p2 = dv*(a2 + 2.f*fh.x) + bg4.z;
        float p3 = dv*(a3 + 2.f*fh.y) + bg4.w;
        p0 = fmaxf(p0*bns*bng4.x + bnb4.x, 0.f);
        p1 = fmaxf(p1*bns*bng4.y + bnb4.y, 0.f);
        p2 = fmaxf(p2*bns*bng4.z + bnb4.z, 0.f);
        p3 = fmaxf(p3*bns*bng4.w + bnb4.w, 0.f);
        if (half == 0){
            *(float4*)&h[(size_t)node*F + 4*lh] = make_float4(p0,p1,p2,p3);
            *(uint2*)&hb32[(size_t)node*64 + 2*lh] = make_uint2(pk2(p0,p1), pk2(p2,p3));
        }
        za0 += p0; za1 += p1; za2 += p2; za3 += p3;
    }
    if (half == 0)
        *(float4*)&zacc[w][4*lh] = make_float4(za0, za1, za2, za3);
    __syncthreads();
    if (w == 0){
        float4 v0 = *(const float4*)&zacc[0][4*lh];
        float4 v1 = *(const float4*)&zacc[1][4*lh];
        float4 v2 = *(const float4*)&zacc[2][4*lh];
        float4 v3 = *(const float4*)&zacc[3][4*lh];
        float s0 = ((v0.x+v1.x)+(v2.x+v3.x)) / 50.0f;
        float s1 = ((v0.y+v1.y)+(v2.y+v3.y)) / 50.0f;
        float s2 = ((v0.z+v1.z)+(v2.z+v3.z)) / 50.0f;
        float s3 = ((v0.w+v1.w)+(v2.w+v3.w)) / 50.0f;
        if (half == 0)
            *(float4*)&z[(size_t)g*F + 4*lh] = make_float4(s0,s1,s2,s3);
        float s = (s0+s1)+(s2+s3);
        #pragma unroll
        for (int off=1; off<32; off<<=1) s += __shfl_xor(s, off);
        float m = s * (1.f/128.f);
        float d0=s0-m, d1=s1-m, d2=s2-m, d3=s3-m;
        float vv = (d0*d0+d1*d1)+(d2*d2+d3*d3);
        #pragma unroll
        for (int off=1; off<32; off<<=1) vv += __shfl_xor(vv, off);
        float rs = rsqrtf(vv*(1.f/128.f) + 1e-5f);
        float4 lg = *(const float4*)&lnpre_g[4*lh];
        float4 lb = *(const float4*)&lnpre_b[4*lh];
        if (half == 0){
            float o0 = d0*rs*lg.x+lb.x, o1 = d1*rs*lg.y+lb.y;
            float o2 = d2*rs*lg.z+lb.z, o3 = d3*rs*lg.w+lb.w;
            *(uint2*)&znb32[(size_t)g*64 + 2*lh] = make_uint2(pk2(o0,o1), pk2(o2,o3));
        }
    }
}

// ---------------- fused set-transformer: one block per set (QKV -> attn -> Wo+LN1 -> FFN -> LN2 -> gsi) ----
// bf16 LDS tiles use STRIDE 136 shorts (272 B = 17*16: 16B-aligned rows for ds_read_b128,
// 2-way bank alias = free). fp32 tiles use stride 132 floats (528 B, aligned).
// LDS overlay (bytes):
//   [0..34816)       Bw    short[128][136]  weight staging (stages 1,3,4,5)
//   [0..41600)       Sc    float[4][50][52] attn scores (attn only; Bw dead)
//   [41600..68000)   qs | zd1f  float[50][132]
//   [68000..94400)   ks ;  zd1b short[64][136] at 68000  (ks dead after attn)
//   [94400..120800)  vs ;  f1b/zd2b short[64][136] at 94400 (vs dead after attn)
//   [120800..138208) aob   short[64][136]
__global__ __launch_bounds__(256) void k_settf(const unsigned short* __restrict__ znb,
                                               const float* __restrict__ z,
                                               const float* __restrict__ Wq, const float* __restrict__ bq,
                                               const float* __restrict__ Wk, const float* __restrict__ bk,
                                               const float* __restrict__ Wv, const float* __restrict__ bv,
                                               const float* __restrict__ Wo, const float* __restrict__ bo,
                                               const float* __restrict__ ln1_g, const float* __restrict__ ln1_b,
                                               const float* __restrict__ W1, const float* __restrict__ b1,
                                               const float* __restrict__ W2, const float* __restrict__ b2,
                                               const float* __restrict__ ln2_g, const float* __restrict__ ln2_b,
                                               const float* __restrict__ Wgbot, const float* __restrict__ bg,
                                               float* __restrict__ zd2, float* __restrict__ gsi){
    __shared__ __align__(16) char smem[138208];
    short* Bw   = (short*)smem;
    float* Sc   = (float*)smem;
    float* qs   = (float*)(smem + 41600);
    float* ks   = (float*)(smem + 68000);
    float* vs   = (float*)(smem + 94400);
    short* aob  = (short*)(smem + 120800);
    float* zd1f = (float*)(smem + 41600);
    short* zd1b = (short*)(smem + 68000);
    short* f1b  = (short*)(smem + 94400);
    short* zd2b = f1b;

    int t = threadIdx.x;
    int lane = t & 63, w = t >> 6;
    int lr = lane & 15, quad = lane >> 4;
    int s = blockIdx.x;
    const int r0 = s*50;

    // ---- stage 1: QKV (bf16 MFMA from znb, fp32 out to LDS) ----
    {
        int rl = w*16 + lr; if (rl > 49) rl = 49;
        const unsigned short* arow = &znb[(size_t)(r0 + rl)*F];
        for (int zsel=0; zsel<3; ++zsel){
            const float* Wp = (zsel==0)?Wq:(zsel==1)?Wk:Wv;
            const float* bp = (zsel==0)?bq:(zsel==1)?bk:bv;
            float* outp = (zsel==0)?qs:(zsel==1)?ks:vs;
            for (int i=t; i<16384; i+=256){
                int k = i>>7, n = i&127;
                Bw[n*136 + k] = f2bs(Wp[(size_t)k*F + n]);
            }
            __syncthreads();
            f32x4 acc[8];
            #pragma unroll
            for (int j=0;j<8;j++) acc[j] = (f32x4){0.f,0.f,0.f,0.f};
            #pragma unroll
            for (int ks4=0; ks4<4; ++ks4){
                int kb = ks4*32 + quad*8;
                short8 a = *(const short8*)&arow[kb];
                #pragma unroll
                for (int nt=0; nt<8; ++nt){
                    short8 b = *(const short8*)&Bw[(nt*16 + lr)*136 + kb];
                    acc[nt] = __builtin_amdgcn_mfma_f32_16x16x32_bf16(a, b, acc[nt], 0, 0, 0);
                }
            }
            #pragma unroll
            for (int r=0; r<4; ++r){
                int row = w*16 + quad*4 + r;
                if (row < 50){
                    #pragma unroll
                    for (int nt=0; nt<8; ++nt){
                        int col = nt*16 + lr;
                        outp[row*132 + col] = acc[nt][r] + bp[col];
                    }
                }
            }
            __syncthreads();
        }
    }

    // ---- stage 2: attention, one wave per head ----
    {
        int hh = w;
        float* ScH = Sc + hh*50*52;
        int qi = lane;
        if (qi < 50){
            float qreg[32];
            #pragma unroll
            for (int d=0; d<32; ++d) qreg[d] = qs[qi*132 + hh*32 + d];
            for (int ki=0; ki<50; ++ki){
                float acc=0.f;
                #pragma unroll
                for (int d=0; d<32; ++d) acc += qreg[d] * ks[ki*132 + hh*32 + d];
                ScH[qi*52 + ki] = acc * 0.17677669529663687f;
            }
            float m=-1e30f;
            for (int ki=0; ki<50; ++ki) m = fmaxf(m, ScH[qi*52+ki]);
            float sum=0.f;
            for (int ki=0; ki<50; ++ki){ float e=__expf(ScH[qi*52+ki]-m); ScH[qi*52+ki]=e; sum+=e; }
            float inv = 1.f/sum;
            float o[32];
            #pragma unroll
            for (int d=0; d<32; ++d) o[d] = 0.f;
            for (int ki=0; ki<50; ++ki){
                float sc = ScH[qi*52+ki] * inv;
                #pragma unroll
                for (int d=0; d<32; ++d) o[d] += sc * vs[ki*132 + hh*32 + d];
            }
            #pragma unroll
            for (int d=0; d<32; ++d) aob[qi*136 + hh*32 + d] = f2bs(o[d]);
        } else if (qi < 64){
            // zero pad rows so no stale bytes enter MFMA A-operands
            #pragma unroll
            for (int d=0; d<32; ++d) aob[qi*136 + hh*32 + d] = 0;
        }
    }
    __syncthreads();

    // ---- stage 3: ap = ao@Wo + bo; zd1 = LN1(z + ap) -> zd1f (fp32) + zd1b (bf16) ----
    {
        for (int i=t; i<16384; i+=256){
            int k = i>>7, n = i&127;
            Bw[n*136 + k] = f2bs(Wo[(size_t)k*F + n]);
        }
        __syncthreads();
        f32x4 acc[8];
        #pragma unroll
        for (int j=0;j<8;j++) acc[j] = (f32x4){0.f,0.f,0.f,0.f};
        #pragma unroll
        for (int ks4=0; ks4<4; ++ks4){
            int kb = ks4*32 + quad*8;
            short8 a = *(const short8*)&aob[(w*16 + lr)*136 + kb];
            #pragma unroll
            for (int nt=0; nt<8; ++nt){
                short8 b = *(const short8*)&Bw[(nt*16 + lr)*136 + kb];
                acc[nt] = __builtin_amdgcn_mfma_f32_16x16x32_bf16(a, b, acc[nt], 0, 0, 0);
            }
        }
        __syncthreads();   // Bw/aob reads done; qs/ks regions about to be overwritten
        #pragma unroll
        for (int r=0; r<4; ++r){
            int row = w*16 + quad*4 + r;
            float v[8];
            if (row < 50){
                #pragma unroll
                for (int nt=0; nt<8; ++nt){
                    int col = nt*16 + lr;
                    v[nt] = acc[nt][r] + bo[col] + z[(size_t)(r0+row)*F + col];
                }
            } else {
                #pragma unroll
                for (int nt=0; nt<8; ++nt) v[nt] = 0.f;
            }
            float ssum = 0.f;
            #pragma unroll
            for (int nt=0; nt<8; ++nt) ssum += v[nt];
            #pragma unroll
            for (int off=1; off<16; off<<=1) ssum += __shfl_xor(ssum, off);
            float mean = ssum * (1.f/128.f);
            float var = 0.f;
            float d[8];
            #pragma unroll
            for (int nt=0; nt<8; ++nt){ d[nt] = v[nt]-mean; var += d[nt]*d[nt]; }
            #pragma unroll
            for (int off=1; off<16; off<<=1) var += __shfl_xor(var, off);
            float rsv = rsqrtf(var*(1.f/128.f) + 1e-5f);
            if (row < 50){
                #pragma unroll
                for (int nt=0; nt<8; ++nt){
                    int col = nt*16 + lr;
                    float o = d[nt]*rsv*ln1_g[col] + ln1_b[col];
                    zd1f[row*132 + col] = o;
                    zd1b[row*136 + col] = f2bs(o);
                }
            } else {
                #pragma unroll
                for (int nt=0; nt<8; ++nt) zd1b[row*136 + nt*16 + lr] = 0;
            }
        }
    }
    __syncthreads();

    // ---- stage 4: FFN, 8 K-chunks of 128, acc2 in registers ----
    f32x4 acc2[8];
    #pragma unroll
    for (int j=0;j<8;j++) acc2[j] = (f32x4){0.f,0.f,0.f,0.f};
    for (int c=0; c<8; ++c){
        for (int i=t; i<16384; i+=256){
            int k = i>>7, n = i&127;
            Bw[n*136 + k] = f2bs(W1[(size_t)k*FFN_DIM + c*128 + n]);
        }
        __syncthreads();
        f32x4 a1[8];
        #pragma unroll
        for (int j=0;j<8;j++) a1[j] = (f32x4){0.f,0.f,0.f,0.f};
        #pragma unroll
        for (int ks4=0; ks4<4; ++ks4){
            int kb = ks4*32 + quad*8;
            short8 a = *(const short8*)&zd1b[(w*16 + lr)*136 + kb];
            #pragma unroll
            for (int nt=0; nt<8; ++nt){
                short8 b = *(const short8*)&Bw[(nt*16 + lr)*136 + kb];
                a1[nt] = __builtin_amdgcn_mfma_f32_16x16x32_bf16(a, b, a1[nt], 0, 0, 0);
            }
        }
        #pragma unroll
        for (int r=0; r<4; ++r){
            int row = w*16 + quad*4 + r;
            #pragma unroll
            for (int nt=0; nt<8; ++nt){
                int col = nt*16 + lr;
                f1b[row*136 + col] = f2bs(fmaxf(a1[nt][r] + b1[c*128 + col], 0.f));
            }
        }
        __syncthreads();
        for (int i=t; i<16384; i+=256){
            int k = i>>7, n = i&127;
            Bw[n*136 + k] = f2bs(W2[(size_t)(c*128 + k)*F + n]);
        }
        __syncthreads();
        #pragma unroll
        for (int ks4=0; ks4<4; ++ks4){
            int kb = ks4*32 + quad*8;
            short8 a = *(const short8*)&f1b[(w*16 + lr)*136 + kb];
            #pragma unroll
            for (int nt=0; nt<8; ++nt){
                short8 b = *(const short8*)&Bw[(nt*16 + lr)*136 + kb];
                acc2[nt] = __builtin_amdgcn_mfma_f32_16x16x32_bf16(a, b, acc2[nt], 0, 0, 0);
            }
        }
        __syncthreads();
    }

    // ---- stage 5: zd2 = LN2(zd1 + ffn + b2); gsi = zd2 @ Wg_bot + bg ----
    {
        #pragma unroll
        for (int r=0; r<4; ++r){
            int row = w*16 + quad*4 + r;
            float v[8];
            if (row < 50){
                #pragma unroll
                for (int nt=0; nt<8; ++nt){
                    int col = nt*16 + lr;
                    v[nt] = acc2[nt][r] + b2[col] + zd1f[row*132 + col];
                }
            } else {
                #pragma unroll
                for (int nt=0; nt<8; ++nt) v[nt] = 0.f;
            }
            float ssum = 0.f;
            #pragma unroll
            for (int nt=0; nt<8; ++nt) ssum += v[nt];
            #pragma unroll
            for (int off=1; off<16; off<<=1) ssum += __shfl_xor(ssum, off);
            float mean = ssum * (1.f/128.f);
            float var = 0.f;
            float d[8];
            #pragma unroll
            for (int nt=0; nt<8; ++nt){ d[nt] = v[nt]-mean; var += d[nt]*d[nt]; }
            #pragma unroll
            for (int off=1; off<16; off<<=1) var += __shfl_xor(var, off);
            float rsv = rsqrtf(var*(1.f/128.f) + 1e-5f);
            if (row < 50){
                #pragma unroll
                for (int nt=0; nt<8; ++nt){
                    int col = nt*16 + lr;
                    float o = d[nt]*rsv*ln2_g[col] + ln2_b[col];
                    zd2[(size_t)(r0+row)*F + col] = o;
                    zd2b[row*136 + col] = f2bs(o);
                }
            } else {
                #pragma unroll
                for (int nt=0; nt<8; ++nt) zd2b[row*136 + nt*16 + lr] = 0;
            }
        }
        // stage Wg_bot (Bw last read before stage-4-end barrier)
        for (int i=t; i<16384; i+=256){
            int k = i>>7, n = i&127;
            Bw[n*136 + k] = f2bs(Wgbot[(size_t)k*F + n]);
        }
        __syncthreads();
        f32x4 ag[8];
        #pragma unroll
        for (int j=0;j<8;j++) ag[j] = (f32x4){0.f,0.f,0.f,0.f};
        #pragma unroll
        for (int ks4=0; ks4<4; ++ks4){
            int kb = ks4*32 + quad*8;
            short8 a = *(const short8*)&zd2b[(w*16 + lr)*136 + kb];
            #pragma unroll
            for (int nt=0; nt<8; ++nt){
                short8 b = *(const short8*)&Bw[(nt*16 + lr)*136 + kb];
                ag[nt] = __builtin_amdgcn_mfma_f32_16x16x32_bf16(a, b, ag[nt], 0, 0, 0);
            }
        }
        #pragma unroll
        for (int r=0; r<4; ++r){
            int row = w*16 + quad*4 + r;
            if (row < 50){
                #pragma unroll
                for (int nt=0; nt<8; ++nt){
                    int col = nt*16 + lr;
                    gsi[(size_t)(r0+row)*F + col] = ag[nt][r] + bg[col];
                }
            }
        }
    }
}

// ---------------- MFMA gate: 64-row tiles, B from global bf16 Wgb (no LDS, no barriers) ----------------
__global__ __launch_bounds__(256) void k_gate_mfma(const float* __restrict__ h,
                                                   const unsigned short* __restrict__ hb,
                                                   const unsigned short* __restrict__ Wgb,
                                                   const float* __restrict__ gsi, const float* __restrict__ zd2,
                                                   float* __restrict__ out){
    int t = threadIdx.x;
    int lane = t & 63, w = t >> 6;
    int lr = lane & 15, quad = lane >> 4;
    int mrow0 = blockIdx.x*64 + w*16;
    f32x4 acc[8];
    #pragma unroll
    for (int j=0;j<8;j++) acc[j] = (f32x4){0.f,0.f,0.f,0.f};
    #pragma unroll
    for (int ks=0; ks<4; ++ks){
        int kb = ks*32 + quad*8;
        int row = mrow0 + lr;
        if (row >= NN) row = NN-1;
        short8 a = *(const short8*)&hb[(size_t)row*F + kb];
        #pragma unroll
        for (int nt=0; nt<8; ++nt){
            short8 b = *(const short8*)&Wgb[(size_t)(nt*16 + lr)*128 + kb];
            acc[nt] = __builtin_amdgcn_mfma_f32_16x16x32_bf16(a, b, acc[nt], 0, 0, 0);
        }
    }
    #pragma unroll
    for (int r=0; r<4; ++r){
        int row = mrow0 + quad*4 + r;
        if (row >= NN) continue;
        int g = row / 50;
        const float* gs = &gsi[(size_t)g*F];
        const float* zs = &zd2[(size_t)g*F];
        const float* hr = &h[(size_t)row*F];
        float* orow = &out[(size_t)row*F];
        #pragma unroll
        for (int nt=0; nt<8; ++nt){
            int col = nt*16 + lr;
            float L = acc[nt][r] + gs[col];
            float gate = 1.f/(1.f + __expf(-L));
            orow[col] = gate*zs[col] + (1.f-gate)*hr[col];
        }
    }
}

extern "C" void kernel_launch(void* const* d_in, const int* in_sizes, int n_in,
                              void* d_out, int out_size, void* d_ws, size_t ws_size,
                              hipStream_t stream) {
    const float* x      = (const float*)d_in[0];
    const int*   ei     = (const int*)d_in[1];
    const float* W_gcn  = (const float*)d_in[4];
    const float* b_gcn  = (const float*)d_in[5];
    const float* bn_g   = (const float*)d_in[6];
    const float* bn_b   = (const float*)d_in[7];
    const float* lnpre_g= (const float*)d_in[8];
    const float* lnpre_b= (const float*)d_in[9];
    const float* Wq     = (const float*)d_in[10];
    const float* bq     = (const float*)d_in[11];
    const float* Wk     = (const float*)d_in[12];
    const float* bk     = (const float*)d_in[13];
    const float* Wv     = (const float*)d_in[14];
    const float* bv     = (const float*)d_in[15];
    const float* Wo     = (const float*)d_in[16];
    const float* bo     = (const float*)d_in[17];
    const float* ln1_g  = (const float*)d_in[18];
    const float* ln1_b  = (const float*)d_in[19];
    const float* W1     = (const float*)d_in[20];
    const float* b1     = (const float*)d_in[21];
    const float* W2     = (const float*)d_in[22];
    const float* b2     = (const float*)d_in[23];
    const float* ln2_g  = (const float*)d_in[24];
    const float* ln2_b  = (const float*)d_in[25];
    const float* Wg     = (const float*)d_in[26];
    const float* bg     = (const float*)d_in[27];
    float* out = (float*)d_out;
    char* ws = (char*)d_ws;

    // workspace layout
    size_t o = 0;
    unsigned char* xws8 = (unsigned char*)(ws + o); o += (size_t)NN*F; // 12.8 MB (fp8)
    float* h     = (float*)(ws + o); o += (size_t)NN*F*4;            // 51.2 MB
    unsigned short* hb = (unsigned short*)(ws + o); o += (size_t)NN*F*2; // 25.6 MB (bf16)
    int*   cnt   = (int*)(ws + o);   o += (size_t)NN*4;
    int*   nstart= (int*)(ws + o);   o += (size_t)NN*4;
    int*   ebuf  = (int*)(ws + o);   o += (size_t)NB*BCAP*4;         // 9.6 MB
    int*   ebuf2 = (int*)(ws + o);   o += (size_t)NB*BCAP*4;         // 9.6 MB
    float* dinv  = (float*)(ws + o); o += (size_t)NN*4;
    int*   bcursor=(int*)(ws + o);   o += 1024*4;
    unsigned short* Wgb = (unsigned short*)(ws + o); o += 16384*2;   // 32 KB bf16 Wg_top^T
    float* z     = (float*)(ws + o); o += (size_t)NG*F*4;
    unsigned short* znb = (unsigned short*)(ws + o); o += (size_t)NG*F*2;
    float* zd2   = (float*)(ws + o); o += (size_t)NG*F*4;
    float* gsi   = (float*)(ws + o); o += (size_t)NG*F*4;

    // ---- GCN phase ----
    k_init<<<1, 1024, 0, stream>>>(bcursor, Wg, Wgb);
    k_scatter2<<<SC_BLOCKS, 1024, 0, stream>>>(ei, bcursor, ebuf);
    k_sort<<<NB, 256, 0, stream>>>(ebuf, bcursor, cnt, dinv, nstart, ebuf2);
    k_xws<<<(NN+127)/128, 256, 0, stream>>>(x, W_gcn, dinv, xws8);
    k_aggpool<<<NG, 256, 0, stream>>>(xws8, nstart, cnt, dinv, b_gcn, bn_g, bn_b, ebuf2,
                                      lnpre_g, lnpre_b, h, hb, z, znb);

    // ---- fused set transformer (one dispatch) ----
    k_settf<<<NS, 256, 0, stream>>>(znb, z, Wq, bq, Wk, bk, Wv, bv, Wo, bo,
                                    ln1_g, ln1_b, W1, b1, W2, b2, ln2_g, ln2_b,
                                    Wg + (size_t)F*F, bg, zd2, gsi);

    // ---- gated fusion -> output ----
    k_gate_mfma<<<(NN+63)/64, 256, 0, stream>>>(h, hb, Wgb, gsi, zd2, out);
}

// Round 10
// 330.818 us; speedup vs baseline: 1.1743x; 1.1743x over previous
//
#include <hip/hip_runtime.h>
#include <hip/hip_bf16.h>
#include <cstddef>

#define NN 100000
#define NE 1600000
#define NG 2000
#define NS 40
#define INF 64
#define F 128
#define FFN_DIM 1024
#define NB 782            // ceil(100000/128) buckets of 128 nodes
#define BCAP 3072         // fixed bucket capacity (mean 2048, sigma 45 -> 19+ sigma margin)
#define SC_BLOCKS 512
#define SC_CHUNK 3125     // 512*3125 = 1.6M edges exactly
#define KSPLIT 8

using bf16 = __hip_bfloat16;
typedef __attribute__((ext_vector_type(8))) short short8;
typedef __attribute__((ext_vector_type(4))) float f32x4;
typedef __attribute__((ext_vector_type(2))) float f32x2;

__device__ __forceinline__ short f2bs(float f){
    union { bf16 b; short s; } u; u.b = __float2bfloat16(f); return u.s;
}
__device__ __forceinline__ unsigned int pk2(float a, float b){
    return (unsigned int)(unsigned short)f2bs(a) | ((unsigned int)(unsigned short)f2bs(b) << 16);
}

// ---------------- init: bucket cursors + ALL weight tables -> transposed bf16 [n][k] ----------------
__global__ __launch_bounds__(256) void k_initw(int* __restrict__ bcursor,
                                               const float* __restrict__ Wq, const float* __restrict__ Wk,
                                               const float* __restrict__ Wv, const float* __restrict__ W1,
                                               const float* __restrict__ W2, const float* __restrict__ Wg,
                                               unsigned short* __restrict__ Wqb, unsigned short* __restrict__ Wkb,
                                               unsigned short* __restrict__ Wvb, unsigned short* __restrict__ W1b,
                                               unsigned short* __restrict__ W2b, unsigned short* __restrict__ Wgb){
    int t = blockIdx.x*256 + threadIdx.x;
    int stride = gridDim.x*256;
    for (int i=t; i<NB; i+=stride) bcursor[i] = i*BCAP;
    for (int i=t; i<16384; i+=stride){
        int k = i>>7, n = i&127;
        Wqb[n*128+k] = (unsigned short)f2bs(Wq[(size_t)k*F+n]);
        Wkb[n*128+k] = (unsigned short)f2bs(Wk[(size_t)k*F+n]);
        Wvb[n*128+k] = (unsigned short)f2bs(Wv[(size_t)k*F+n]);
        Wgb[n*128+k] = (unsigned short)f2bs(Wg[(size_t)k*F+n]);
    }
    for (int i=t; i<131072; i+=stride){
        int k = i>>10, n = i&1023;   // k in [0,128), n in [0,1024)
        W1b[(size_t)n*128+k] = (unsigned short)f2bs(W1[(size_t)k*FFN_DIM+n]);
    }
    for (int i=t; i<131072; i+=stride){
        int n = i>>10, k = i&1023;   // n in [0,128), k in [0,1024)
        W2b[(size_t)n*1024+k] = (unsigned short)f2bs(W2[(size_t)k*F+n]);
    }
}

// ---------------- xws = (x @ W_gcn) * dinv[row], bf16 MFMA, stored fp8 e4m3 ----------------
__global__ __launch_bounds__(256) void k_xws(const float* __restrict__ x, const float* __restrict__ W,
                                             const float* __restrict__ dinv, unsigned char* __restrict__ xws8){
    __shared__ short Xs[128*72];   // [row][k], stride 72 (K=64)
    __shared__ short Ws[128*72];   // [feature][k], stride 72
    int t = threadIdx.x;
    int rowBase = blockIdx.x * 128;
    #pragma unroll
    for (int i=0;i<32;i++){
        int id = i*256+t; int k = id>>7, n = id&127;
        Ws[n*72 + k] = f2bs(W[id]);
    }
    #pragma unroll
    for (int i=0;i<8;i++){
        int id = i*256+t;              // 2048 float4 slots
        int r = id>>4; int k4 = (id&15)*4;
        int row = rowBase + r; if (row >= NN) row = NN-1;
        float4 v = *(const float4*)&x[(size_t)row*INF + k4];
        *(unsigned int*)&Xs[r*72 + k4]     = pk2(v.x, v.y);
        *(unsigned int*)&Xs[r*72 + k4 + 2] = pk2(v.z, v.w);
    }
    __syncthreads();
    int lane = t & 63, w = t >> 6;
    int lr = lane & 15, quad = lane >> 4;
    f32x4 acc[2][8];
    #pragma unroll
    for (int i=0;i<2;i++)
        #pragma unroll
        for (int j=0;j<8;j++) acc[i][j] = (f32x4){0.f,0.f,0.f,0.f};
    #pragma unroll
    for (int ks=0; ks<2; ++ks){
        int kb = ks*32 + quad*8;
        short8 b0 = *(const short8*)&Xs[((w  )*16 + lr)*72 + kb];
        short8 b1 = *(const short8*)&Xs[((w+4)*16 + lr)*72 + kb];
        #pragma unroll
        for (int mt=0; mt<8; ++mt){
            short8 a = *(const short8*)&Ws[(mt*16 + lr)*72 + kb];
            acc[0][mt] = __builtin_amdgcn_mfma_f32_16x16x32_bf16(a, b0, acc[0][mt], 0, 0, 0);
            acc[1][mt] = __builtin_amdgcn_mfma_f32_16x16x32_bf16(a, b1, acc[1][mt], 0, 0, 0);
        }
    }
    #pragma unroll
    for (int rt=0; rt<2; ++rt){
        int row = rowBase + (w + rt*4)*16 + lr;
        if (row < NN){
            float dv = dinv[row];
            #pragma unroll
            for (int mt=0; mt<8; ++mt){
                int p = __builtin_amdgcn_cvt_pk_fp8_f32(acc[rt][mt][0]*dv, acc[rt][mt][1]*dv, 0, false);
                p     = __builtin_amdgcn_cvt_pk_fp8_f32(acc[rt][mt][2]*dv, acc[rt][mt][3]*dv, p, true);
                *(int*)&xws8[(size_t)row*F + mt*16 + quad*4] = p;
            }
        }
    }
}

// ---------------- binned scatter: pack (row<<7|col&127) into fixed bucket regions ----------------
__global__ __launch_bounds__(1024) void k_scatter2(const int* __restrict__ ei, int* __restrict__ bcursor,
                                                   int* __restrict__ ebuf){
    __shared__ int lh[NB];
    __shared__ int lb[NB];
    int t = threadIdx.x;
    int base = blockIdx.x * SC_CHUNK;
    for (int b=t; b<NB; b+=1024) lh[b] = 0;
    __syncthreads();
    int rr[4], cc[4];
    #pragma unroll
    for (int q=0;q<4;q++){
        int i = t + q*1024;
        bool v = (i < SC_CHUNK);
        int idx = v ? (base + i) : base;
        rr[q] = ei[idx];
        cc[q] = ei[NE + idx];
        if (v) atomicAdd(&lh[cc[q]>>7], 1);
    }
    __syncthreads();
    for (int b=t; b<NB; b+=1024){
        int n = lh[b];
        lb[b] = n ? atomicAdd(&bcursor[b], n) : 0;
        lh[b] = 0;
    }
    __syncthreads();
    #pragma unroll
    for (int q=0;q<4;q++){
        int i = t + q*1024;
        if (i < SC_CHUNK){
            int b = cc[q] >> 7;
            int rk = atomicAdd(&lh[b], 1);
            ebuf[lb[b] + rk] = (rr[q] << 7) | (cc[q] & 127);
        }
    }
}

// ---------------- per-bucket counting sort; LDS-staged output (coalesced ebuf2 writes) ----------------
__global__ __launch_bounds__(256) void k_sort(const int* __restrict__ ebuf, const int* __restrict__ bcursor,
                                              int* __restrict__ cnt, float* __restrict__ dinv,
                                              int* __restrict__ nstart, int* __restrict__ ebuf2){
    __shared__ int lh[128];
    __shared__ int s[128];
    __shared__ int lcur[128];
    __shared__ int sorted[BCAP];
    int t = threadIdx.x;
    int b = blockIdx.x;
    int e0 = b * BCAP;
    int nE = bcursor[b] - e0;
    if (t < 128) lh[t] = 0;
    __syncthreads();
    for (int i=t; i<nE; i+=256) atomicAdd(&lh[ebuf[e0+i] & 127], 1);
    __syncthreads();
    int c = (t < 128) ? lh[t] : 0;
    if (t < 128) s[t] = c;
    __syncthreads();
    #pragma unroll
    for (int off=1; off<128; off<<=1){
        int v = (t >= off && t < 128) ? s[t-off] : 0;
        __syncthreads();
        if (t < 128) s[t] += v;
        __syncthreads();
    }
    int node = b*128 + t;
    if (t < 128){
        int excl = s[t] - c;
        lcur[t] = excl;
        if (node < NN){
            nstart[node] = e0 + excl;
            cnt[node] = c;
            dinv[node] = rsqrtf((float)c + 2.0f);
        }
    }
    __syncthreads();
    for (int i=t; i<nE; i+=256){
        int v = ebuf[e0 + i];
        int nl = v & 127;
        int rk = atomicAdd(&lcur[nl], 1);
        sorted[rk] = (v >> 7) << 5;   // row * 32 (uint-word offset into xws8)
    }
    __syncthreads();
    for (int i=t; i<nE; i+=256) ebuf2[e0 + i] = sorted[i];
}

// ---------------- fused: CSR gather + GCN epilogue + BN + ReLU -> h,hb + pool -> z, znb ----------------
__global__ __launch_bounds__(256) void k_aggpool(const unsigned char* __restrict__ xws8,
                                                 const int* __restrict__ nstart, const int* __restrict__ cnt,
                                                 const float* __restrict__ dinv, const float* __restrict__ b_gcn,
                                                 const float* __restrict__ bn_g, const float* __restrict__ bn_b,
                                                 const int* __restrict__ ebuf2,
                                                 const float* __restrict__ lnpre_g, const float* __restrict__ lnpre_b,
                                                 float* __restrict__ h, unsigned short* __restrict__ hb,
                                                 float* __restrict__ z, unsigned short* __restrict__ znb){
    __shared__ float zacc[4][128];
    int t = threadIdx.x;
    int lane = t & 63, w = t >> 6;
    int half = lane >> 5, lh = lane & 31;
    int g = blockIdx.x;
    const unsigned int* xw32 = (const unsigned int*)xws8;   // row stride = 32 uints
    unsigned int* hb32 = (unsigned int*)hb;
    unsigned int* znb32 = (unsigned int*)znb;

    float4 bg4  = *(const float4*)&b_gcn[4*lh];
    float4 bng4 = *(const float4*)&bn_g[4*lh];
    float4 bnb4 = *(const float4*)&bn_b[4*lh];
    const float bns = rsqrtf(1.f + 1e-5f);

    float za0=0.f, za1=0.f, za2=0.f, za3=0.f;

    for (int i = w; i < 50; i += 4){
        int node = g*50 + i;
        int s0n = nstart[node]; int dg = cnt[node]; float dv = dinv[node];
        unsigned int us = xw32[node*32 + lh];   // self-loop, issued early
        float a0=0.f, a1=0.f, a2=0.f, a3=0.f;
        int j=0;
        for (; j+8<=dg; j+=8){
            int r0 = ebuf2[s0n+j+0+half];
            int r1 = ebuf2[s0n+j+2+half];
            int r2 = ebuf2[s0n+j+4+half];
            int r3 = ebuf2[s0n+j+6+half];
            unsigned int u0 = xw32[r0 + lh];
            unsigned int u1 = xw32[r1 + lh];
            unsigned int u2 = xw32[r2 + lh];
            unsigned int u3 = xw32[r3 + lh];
            f32x2 l0 = __builtin_amdgcn_cvt_pk_f32_fp8(u0, false);
            f32x2 h0 = __builtin_amdgcn_cvt_pk_f32_fp8(u0, true);
            f32x2 l1 = __builtin_amdgcn_cvt_pk_f32_fp8(u1, false);
            f32x2 h1 = __builtin_amdgcn_cvt_pk_f32_fp8(u1, true);
            f32x2 l2 = __builtin_amdgcn_cvt_pk_f32_fp8(u2, false);
            f32x2 h2 = __builtin_amdgcn_cvt_pk_f32_fp8(u2, true);
            f32x2 l3 = __builtin_amdgcn_cvt_pk_f32_fp8(u3, false);
            f32x2 h3 = __builtin_amdgcn_cvt_pk_f32_fp8(u3, true);
            a0 += (l0.x + l1.x) + (l2.x + l3.x);
            a1 += (l0.y + l1.y) + (l2.y + l3.y);
            a2 += (h0.x + h1.x) + (h2.x + h3.x);
            a3 += (h0.y + h1.y) + (h2.y + h3.y);
        }
        for (; j+2<=dg; j+=2){
            int r0 = ebuf2[s0n+j+half];
            unsigned int u0 = xw32[r0 + lh];
            f32x2 l0 = __builtin_amdgcn_cvt_pk_f32_fp8(u0, false);
            f32x2 h0 = __builtin_amdgcn_cvt_pk_f32_fp8(u0, true);
            a0 += l0.x; a1 += l0.y; a2 += h0.x; a3 += h0.y;
        }
        if (j < dg && half == 0){
            int r0 = ebuf2[s0n+j];
            unsigned int u0 = xw32[r0 + lh];
            f32x2 l0 = __builtin_amdgcn_cvt_pk_f32_fp8(u0, false);
            f32x2 h0 = __builtin_amdgcn_cvt_pk_f32_fp8(u0, true);
            a0 += l0.x; a1 += l0.y; a2 += h0.x; a3 += h0.y;
        }
        a0 += __shfl_xor(a0, 32);
        a1 += __shfl_xor(a1, 32);
        a2 += __shfl_xor(a2, 32);
        a3 += __shfl_xor(a3, 32);
        f32x2 fl = __builtin_amdgcn_cvt_pk_f32_fp8(us, false);
        f32x2 fh = __builtin_amdgcn_cvt_pk_f32_fp8(us, true);
        float p0 = dv*(a0 + 2.f*fl.x) + bg4.x;
        float p1 = dv*(a1 + 2.f*fl.y) + bg4.y;
        float p2 = dv*(a2 + 2.f*fh.x) + bg4.z;
        float p3 = dv*(a3 + 2.f*fh.y) + bg4.w;
        p0 = fmaxf(p0*bns*bng4.x + bnb4.x, 0.f);
        p1 = fmaxf(p1*bns*bng4.y + bnb4.y, 0.f);
        p2 = fmaxf(p2*bns*bng4.z + bnb4.z, 0.f);
        p3 = fmaxf(p3*bns*bng4.w + bnb4.w, 0.f);
        if (half == 0){
            *(float4*)&h[(size_t)node*F + 4*lh] = make_float4(p0,p1,p2,p3);
            *(uint2*)&hb32[(size_t)node*64 + 2*lh] = make_uint2(pk2(p0,p1), pk2(p2,p3));
        }
        za0 += p0; za1 += p1; za2 += p2; za3 += p3;
    }
    if (half == 0)
        *(float4*)&zacc[w][4*lh] = make_float4(za0, za1, za2, za3);
    __syncthreads();
    if (w == 0){
        float4 v0 = *(const float4*)&zacc[0][4*lh];
        float4 v1 = *(const float4*)&zacc[1][4*lh];
        float4 v2 = *(const float4*)&zacc[2][4*lh];
        float4 v3 = *(const float4*)&zacc[3][4*lh];
        float s0 = ((v0.x+v1.x)+(v2.x+v3.x)) / 50.0f;
        float s1 = ((v0.y+v1.y)+(v2.y+v3.y)) / 50.0f;
        float s2 = ((v0.z+v1.z)+(v2.z+v3.z)) / 50.0f;
        float s3 = ((v0.w+v1.w)+(v2.w+v3.w)) / 50.0f;
        if (half == 0)
            *(float4*)&z[(size_t)g*F + 4*lh] = make_float4(s0,s1,s2,s3);
        float s = (s0+s1)+(s2+s3);
        #pragma unroll
        for (int off=1; off<32; off<<=1) s += __shfl_xor(s, off);
        float m = s * (1.f/128.f);
        float d0=s0-m, d1=s1-m, d2=s2-m, d3=s3-m;
        float vv = (d0*d0+d1*d1)+(d2*d2+d3*d3);
        #pragma unroll
        for (int off=1; off<32; off<<=1) vv += __shfl_xor(vv, off);
        float rs = rsqrtf(vv*(1.f/128.f) + 1e-5f);
        float4 lg = *(const float4*)&lnpre_g[4*lh];
        float4 lb = *(const float4*)&lnpre_b[4*lh];
        if (half == 0){
            float o0 = d0*rs*lg.x+lb.x, o1 = d1*rs*lg.y+lb.y;
            float o2 = d2*rs*lg.z+lb.z, o3 = d3*rs*lg.w+lb.w;
            *(uint2*)&znb32[(size_t)g*64 + 2*lh] = make_uint2(pk2(o0,o1), pk2(o2,o3));
        }
    }
}

// ---------------- QKV: 64-row tiles, B direct from global bf16 tables (no LDS) ----------------
__global__ __launch_bounds__(256) void k_qkv_g(const unsigned short* __restrict__ znb,
                                               const unsigned short* __restrict__ Wqb,
                                               const unsigned short* __restrict__ Wkb,
                                               const unsigned short* __restrict__ Wvb,
                                               const float* __restrict__ bq, const float* __restrict__ bk,
                                               const float* __restrict__ bv,
                                               float* __restrict__ Cq, float* __restrict__ Ck,
                                               float* __restrict__ Cv){
    int zsel = blockIdx.z;
    const unsigned short* B = (zsel==0)?Wqb:(zsel==1)?Wkb:Wvb;
    const float* bias = (zsel==0)?bq:(zsel==1)?bk:bv;
    float* C = (zsel==0)?Cq:(zsel==1)?Ck:Cv;
    int t = threadIdx.x;
    int lane = t & 63, w = t >> 6;
    int lr = lane & 15, quad = lane >> 4;
    int mrow0 = blockIdx.x*64 + w*16;
    f32x4 acc[8];
    #pragma unroll
    for (int j=0;j<8;j++) acc[j] = (f32x4){0.f,0.f,0.f,0.f};
    #pragma unroll
    for (int ks=0; ks<4; ++ks){
        int kb = ks*32 + quad*8;
        int row = mrow0 + lr;
        if (row >= NG) row = NG-1;
        short8 a = *(const short8*)&znb[(size_t)row*F + kb];
        #pragma unroll
        for (int nt=0; nt<8; ++nt){
            short8 b = *(const short8*)&B[(size_t)(nt*16 + lr)*128 + kb];
            acc[nt] = __builtin_amdgcn_mfma_f32_16x16x32_bf16(a, b, acc[nt], 0, 0, 0);
        }
    }
    #pragma unroll
    for (int r=0; r<4; ++r){
        int row = mrow0 + quad*4 + r;
        if (row >= NG) continue;
        #pragma unroll
        for (int nt=0; nt<8; ++nt){
            int col = nt*16 + lr;
            C[(size_t)row*F + col] = acc[nt][r] + bias[col];
        }
    }
}

// ---------------- FFN1: 64-row x 128-col tiles, B from global W1b, ReLU, bf16 out ----------------
__global__ __launch_bounds__(256) void k_ffn1_g(const unsigned short* __restrict__ zd1b,
                                                const unsigned short* __restrict__ W1b,
                                                const float* __restrict__ b1,
                                                unsigned short* __restrict__ ffn1b){
    int t = threadIdx.x;
    int lane = t & 63, w = t >> 6;
    int lr = lane & 15, quad = lane >> 4;
    int mrow0 = blockIdx.x*64 + w*16;
    int colBase = blockIdx.y*128;
    f32x4 acc[8];
    #pragma unroll
    for (int j=0;j<8;j++) acc[j] = (f32x4){0.f,0.f,0.f,0.f};
    #pragma unroll
    for (int ks=0; ks<4; ++ks){
        int kb = ks*32 + quad*8;
        int row = mrow0 + lr;
        if (row >= NG) row = NG-1;
        short8 a = *(const short8*)&zd1b[(size_t)row*F + kb];
        #pragma unroll
        for (int nt=0; nt<8; ++nt){
            short8 b = *(const short8*)&W1b[(size_t)(colBase + nt*16 + lr)*128 + kb];
            acc[nt] = __builtin_amdgcn_mfma_f32_16x16x32_bf16(a, b, acc[nt], 0, 0, 0);
        }
    }
    #pragma unroll
    for (int r=0; r<4; ++r){
        int row = mrow0 + quad*4 + r;
        if (row >= NG) continue;
        #pragma unroll
        for (int nt=0; nt<8; ++nt){
            int col = colBase + nt*16 + lr;
            ffn1b[(size_t)row*FFN_DIM + col] = (unsigned short)f2bs(fmaxf(acc[nt][r] + b1[col], 0.f));
        }
    }
}

// ---------------- FFN2 split-K: 64-row tiles, z-th 128-chunk of K, fp32 partials ----------------
__global__ __launch_bounds__(256) void k_ffn2_g(const unsigned short* __restrict__ ffn1b,
                                                const unsigned short* __restrict__ W2b,
                                                float* __restrict__ part){
    int t = threadIdx.x;
    int lane = t & 63, w = t >> 6;
    int lr = lane & 15, quad = lane >> 4;
    int mrow0 = blockIdx.x*64 + w*16;
    int kbeg = blockIdx.z*128;
    f32x4 acc[8];
    #pragma unroll
    for (int j=0;j<8;j++) acc[j] = (f32x4){0.f,0.f,0.f,0.f};
    #pragma unroll
    for (int ks=0; ks<4; ++ks){
        int kb = ks*32 + quad*8;
        int row = mrow0 + lr;
        if (row >= NG) row = NG-1;
        short8 a = *(const short8*)&ffn1b[(size_t)row*FFN_DIM + kbeg + kb];
        #pragma unroll
        for (int nt=0; nt<8; ++nt){
            short8 b = *(const short8*)&W2b[(size_t)(nt*16 + lr)*1024 + kbeg + kb];
            acc[nt] = __builtin_amdgcn_mfma_f32_16x16x32_bf16(a, b, acc[nt], 0, 0, 0);
        }
    }
    float* Cp = part + (size_t)blockIdx.z*NG*F;
    #pragma unroll
    for (int r=0; r<4; ++r){
        int row = mrow0 + quad*4 + r;
        if (row >= NG) continue;
        #pragma unroll
        for (int nt=0; nt<8; ++nt){
            int col = nt*16 + lr;
            Cp[(size_t)row*F + col] = acc[nt][r];
        }
    }
}

// ---------------- fused: ap = ao@Wo + bo; zd1 = LN(z + ap) (+ bf16 sidecar zd1b) ----------------
__global__ __launch_bounds__(256) void k_wo_ln(const float* __restrict__ ao, const float* __restrict__ Wo,
                                               const float* __restrict__ bo, const float* __restrict__ z,
                                               const float* __restrict__ g, const float* __restrict__ b,
                                               float* __restrict__ zd1, unsigned short* __restrict__ zd1b){
    __shared__ float As[32*36];
    __shared__ float Bs[32*128];
    int t = threadIdx.x;
    int rowBase = blockIdx.x*32;
    int c0 = (t&31)*4, r0 = (t>>5)*4;
    unsigned int* zd1b32 = (unsigned int*)zd1b;
    float acc[4][4];
    #pragma unroll
    for (int i=0;i<4;i++){ acc[i][0]=0.f; acc[i][1]=0.f; acc[i][2]=0.f; acc[i][3]=0.f; }
    for (int kb=0; kb<F; kb+=32){
        #pragma unroll
        for (int i=0;i<4;i++){
            int id = i*256+t; int kk = id&31; int r = id>>5;
            int row = rowBase + r;
            As[kk*36+r] = (row<NG) ? ao[(size_t)row*F + kb + kk] : 0.f;
        }
        #pragma unroll
        for (int i=0;i<16;i++){
            int id = i*256+t; int c = id&127; int kk = id>>7;
            Bs[kk*128+c] = Wo[(size_t)(kb+kk)*F + c];
        }
        __syncthreads();
        for (int kk=0;kk<32;kk++){
            float4 a = *(const float4*)&As[kk*36+r0];
            float4 bv = *(const float4*)&Bs[kk*128+c0];
            float av[4]={a.x,a.y,a.z,a.w}; float bb[4]={bv.x,bv.y,bv.z,bv.w};
            #pragma unroll
            for(int i=0;i<4;i++)
                #pragma unroll
                for(int j=0;j<4;j++) acc[i][j] += av[i]*bb[j];
        }
        __syncthreads();
    }
    float4 bo4 = *(const float4*)&bo[c0];
    float4 g4  = *(const float4*)&g[c0];
    float4 b4  = *(const float4*)&b[c0];
    #pragma unroll
    for (int i=0;i<4;i++){
        int row = rowBase + r0 + i;
        float v0=0.f,v1=0.f,v2=0.f,v3=0.f;
        if (row < NG){
            float4 zr = *(const float4*)&z[(size_t)row*F + c0];
            v0 = acc[i][0] + bo4.x + zr.x;
            v1 = acc[i][1] + bo4.y + zr.y;
            v2 = acc[i][2] + bo4.z + zr.z;
            v3 = acc[i][3] + bo4.w + zr.w;
        }
        float s = (v0+v1)+(v2+v3);
        #pragma unroll
        for (int off=1; off<32; off<<=1) s += __shfl_xor(s, off);
        float m = s * (1.f/128.f);
        float d0=v0-m, d1=v1-m, d2=v2-m, d3=v3-m;
        float vv = (d0*d0+d1*d1)+(d2*d2+d3*d3);
        #pragma unroll
        for (int off=1; off<32; off<<=1) vv += __shfl_xor(vv, off);
        float rs = rsqrtf(vv*(1.f/128.f) + 1e-5f);
        if (row < NG){
            float o0 = d0*rs*g4.x+b4.x, o1 = d1*rs*g4.y+b4.y;
            float o2 = d2*rs*g4.z+b4.z, o3 = d3*rs*g4.w+b4.w;
            *(float4*)&zd1[(size_t)row*F + c0] = make_float4(o0,o1,o2,o3);
            *(uint2*)&zd1b32[(size_t)row*(F/2) + c0/2] = make_uint2(pk2(o0,o1), pk2(o2,o3));
        }
    }
}

// ---------------- fused: zd2 = LN(zd1 + sum(part) + b2); gsi = zd2 @ Wg_bot + bg ----------------
__global__ __launch_bounds__(256) void k_ln_red_gsi(const float* __restrict__ A, const float* __restrict__ part,
                                                    const float* __restrict__ bias, const float* __restrict__ g,
                                                    const float* __restrict__ b, const float* __restrict__ Wb,
                                                    const float* __restrict__ bg, float* __restrict__ zd2,
                                                    float* __restrict__ gsi){
    __shared__ float Zs[4][128];
    __shared__ float Bs[32*128];
    int t = threadIdx.x; int lane = t&63;
    int rquad = t>>6;
    int row = blockIdx.x*4 + rquad;
    int i0 = row*F + 2*lane;
    float x0 = A[i0] + bias[2*lane], x1 = A[i0+1] + bias[2*lane+1];
    #pragma unroll
    for (int zz=0; zz<KSPLIT; ++zz){
        x0 += part[(size_t)zz*NG*F + i0];
        x1 += part[(size_t)zz*NG*F + i0 + 1];
    }
    float s = x0+x1;
    for (int off=1; off<64; off<<=1) s += __shfl_xor(s, off);
    float m = s * (1.f/128.f);
    float d0 = x0-m, d1 = x1-m;
    float vv = d0*d0 + d1*d1;
    for (int off=1; off<64; off<<=1) vv += __shfl_xor(vv, off);
    float rs = rsqrtf(vv*(1.f/128.f) + 1e-5f);
    float o0 = d0*rs*g[2*lane]   + b[2*lane];
    float o1 = d1*rs*g[2*lane+1] + b[2*lane+1];
    zd2[i0]   = o0;
    zd2[i0+1] = o1;
    Zs[rquad][2*lane]   = o0;
    Zs[rquad][2*lane+1] = o1;
    __syncthreads();
    int col = t & 127, rp = t >> 7;
    float a0=0.f, a1=0.f;
    for (int kb=0; kb<F; kb+=32){
        #pragma unroll
        for (int i=0;i<16;i++){
            int id = i*256+t; int c = id&127; int kk = id>>7;
            Bs[kk*128+c] = Wb[(size_t)(kb+kk)*F + c];
        }
        __syncthreads();
        for (int kk=0;kk<32;kk++){
            float w = Bs[kk*128+col];
            a0 += Zs[rp][kb+kk]   * w;
            a1 += Zs[rp+2][kb+kk] * w;
        }
        __syncthreads();
    }
    float bgc = bg[col];
    gsi[(size_t)(blockIdx.x*4 + rp)*F + col]     = a0 + bgc;
    gsi[(size_t)(blockIdx.x*4 + rp + 2)*F + col] = a1 + bgc;
}

// ---------------- attention: one block per (set, head) ----------------
__global__ __launch_bounds__(256) void k_attn(const float* __restrict__ q, const float* __restrict__ k,
                                              const float* __restrict__ v, float* __restrict__ o){
    __shared__ float Qs[1600], Ks[1600], Vs[1600], Sc[2500];
    int t = threadIdx.x;
    int s = blockIdx.x >> 2; int hh = blockIdx.x & 3;
    for (int idx=t; idx<1600; idx+=256){
        int i = idx>>5, d = idx&31;
        size_t gi = (size_t)(s*50+i)*F + hh*32 + d;
        Qs[idx]=q[gi]; Ks[idx]=k[gi]; Vs[idx]=v[gi];
    }
    __syncthreads();
    for (int idx=t; idx<2500; idx+=256){
        int qi = idx/50, ki = idx%50;
        float acc=0.f;
        #pragma unroll 8
        for (int d=0;d<32;d++) acc += Qs[qi*32+d]*Ks[ki*32+d];
        Sc[idx] = acc * 0.17677669529663687f;   // 1/sqrt(32)
    }
    __syncthreads();
    if (t < 50){
        float m=-1e30f;
        for (int j=0;j<50;j++) m = fmaxf(m, Sc[t*50+j]);
        float sum=0.f;
        for (int j=0;j<50;j++){ float e=__expf(Sc[t*50+j]-m); Sc[t*50+j]=e; sum+=e; }
        float inv = 1.f/sum;
        for (int j=0;j<50;j++) Sc[t*50+j] *= inv;
    }
    __syncthreads();
    for (int idx=t; idx<1600; idx+=256){
        int qi = idx>>5, d = idx&31;
        float acc=0.f;
        #pragma unroll 10
        for (int ki=0;ki<50;ki++) acc += Sc[qi*50+ki]*Vs[ki*32+d];
        o[(size_t)(s*50+qi)*F + hh*32 + d] = acc;
    }
}

// ---------------- MFMA gate: 64-row tiles, B from global bf16 Wgb (no LDS, no barriers) ----------------
__global__ __launch_bounds__(256) void k_gate_mfma(const float* __restrict__ h,
                                                   const unsigned short* __restrict__ hb,
                                                   const unsigned short* __restrict__ Wgb,
                                                   const float* __restrict__ gsi, const float* __restrict__ zd2,
                                                   float* __restrict__ out){
    int t = threadIdx.x;
    int lane = t & 63, w = t >> 6;
    int lr = lane & 15, quad = lane >> 4;
    int mrow0 = blockIdx.x*64 + w*16;
    f32x4 acc[8];
    #pragma unroll
    for (int j=0;j<8;j++) acc[j] = (f32x4){0.f,0.f,0.f,0.f};
    #pragma unroll
    for (int ks=0; ks<4; ++ks){
        int kb = ks*32 + quad*8;
        int row = mrow0 + lr;
        if (row >= NN) row = NN-1;
        short8 a = *(const short8*)&hb[(size_t)row*F + kb];
        #pragma unroll
        for (int nt=0; nt<8; ++nt){
            short8 b = *(const short8*)&Wgb[(size_t)(nt*16 + lr)*128 + kb];
            acc[nt] = __builtin_amdgcn_mfma_f32_16x16x32_bf16(a, b, acc[nt], 0, 0, 0);
        }
    }
    #pragma unroll
    for (int r=0; r<4; ++r){
        int row = mrow0 + quad*4 + r;
        if (row >= NN) continue;
        int g = row / 50;
        const float* gs = &gsi[(size_t)g*F];
        const float* zs = &zd2[(size_t)g*F];
        const float* hr = &h[(size_t)row*F];
        float* orow = &out[(size_t)row*F];
        #pragma unroll
        for (int nt=0; nt<8; ++nt){
            int col = nt*16 + lr;
            float L = acc[nt][r] + gs[col];
            float gate = 1.f/(1.f + __expf(-L));
            orow[col] = gate*zs[col] + (1.f-gate)*hr[col];
        }
    }
}

extern "C" void kernel_launch(void* const* d_in, const int* in_sizes, int n_in,
                              void* d_out, int out_size, void* d_ws, size_t ws_size,
                              hipStream_t stream) {
    const float* x      = (const float*)d_in[0];
    const int*   ei     = (const int*)d_in[1];
    const float* W_gcn  = (const float*)d_in[4];
    const float* b_gcn  = (const float*)d_in[5];
    const float* bn_g   = (const float*)d_in[6];
    const float* bn_b   = (const float*)d_in[7];
    const float* lnpre_g= (const float*)d_in[8];
    const float* lnpre_b= (const float*)d_in[9];
    const float* Wq     = (const float*)d_in[10];
    const float* bq     = (const float*)d_in[11];
    const float* Wk     = (const float*)d_in[12];
    const float* bk     = (const float*)d_in[13];
    const float* Wv     = (const float*)d_in[14];
    const float* bv     = (const float*)d_in[15];
    const float* Wo     = (const float*)d_in[16];
    const float* bo     = (const float*)d_in[17];
    const float* ln1_g  = (const float*)d_in[18];
    const float* ln1_b  = (const float*)d_in[19];
    const float* W1     = (const float*)d_in[20];
    const float* b1     = (const float*)d_in[21];
    const float* W2     = (const float*)d_in[22];
    const float* b2     = (const float*)d_in[23];
    const float* ln2_g  = (const float*)d_in[24];
    const float* ln2_b  = (const float*)d_in[25];
    const float* Wg     = (const float*)d_in[26];
    const float* bg     = (const float*)d_in[27];
    float* out = (float*)d_out;
    char* ws = (char*)d_ws;

    // workspace layout
    size_t o = 0;
    unsigned char* xws8 = (unsigned char*)(ws + o); o += (size_t)NN*F; // 12.8 MB (fp8)
    float* h     = (float*)(ws + o); o += (size_t)NN*F*4;            // 51.2 MB
    unsigned short* hb = (unsigned short*)(ws + o); o += (size_t)NN*F*2; // 25.6 MB (bf16)
    int*   cnt   = (int*)(ws + o);   o += (size_t)NN*4;
    int*   nstart= (int*)(ws + o);   o += (size_t)NN*4;
    int*   ebuf  = (int*)(ws + o);   o += (size_t)NB*BCAP*4;         // 9.6 MB
    int*   ebuf2 = (int*)(ws + o);   o += (size_t)NB*BCAP*4;         // 9.6 MB
    float* dinv  = (float*)(ws + o); o += (size_t)NN*4;
    int*   bcursor=(int*)(ws + o);   o += 1024*4;
    unsigned short* Wgb = (unsigned short*)(ws + o); o += 16384*2;
    unsigned short* Wqb = (unsigned short*)(ws + o); o += 16384*2;
    unsigned short* Wkb = (unsigned short*)(ws + o); o += 16384*2;
    unsigned short* Wvb = (unsigned short*)(ws + o); o += 16384*2;
    unsigned short* W1b = (unsigned short*)(ws + o); o += (size_t)131072*2;  // 256 KB
    unsigned short* W2b = (unsigned short*)(ws + o); o += (size_t)131072*2;  // 256 KB
    float* z     = (float*)(ws + o); o += (size_t)NG*F*4;
    unsigned short* znb = (unsigned short*)(ws + o); o += (size_t)NG*F*2;
    float* qb    = (float*)(ws + o); o += (size_t)NG*F*4;
    float* kb2   = (float*)(ws + o); o += (size_t)NG*F*4;
    float* vb    = (float*)(ws + o); o += (size_t)NG*F*4;
    float* ao    = (float*)(ws + o); o += (size_t)NG*F*4;
    float* zd1   = (float*)(ws + o); o += (size_t)NG*F*4;
    unsigned short* zd1b = (unsigned short*)(ws + o); o += (size_t)NG*F*2;
    unsigned short* ffn1b = (unsigned short*)(ws + o); o += (size_t)NG*FFN_DIM*2; // 4.1 MB
    float* part  = (float*)(ws + o); o += (size_t)KSPLIT*NG*F*4;     // 8.2 MB
    float* zd2   = (float*)(ws + o); o += (size_t)NG*F*4;
    float* gsi   = (float*)(ws + o); o += (size_t)NG*F*4;

    // ---- GCN phase ----
    k_initw<<<64, 256, 0, stream>>>(bcursor, Wq, Wk, Wv, W1, W2, Wg,
                                    Wqb, Wkb, Wvb, W1b, W2b, Wgb);
    k_scatter2<<<SC_BLOCKS, 1024, 0, stream>>>(ei, bcursor, ebuf);
    k_sort<<<NB, 256, 0, stream>>>(ebuf, bcursor, cnt, dinv, nstart, ebuf2);
    k_xws<<<(NN+127)/128, 256, 0, stream>>>(x, W_gcn, dinv, xws8);
    k_aggpool<<<NG, 256, 0, stream>>>(xws8, nstart, cnt, dinv, b_gcn, bn_g, bn_b, ebuf2,
                                      lnpre_g, lnpre_b, h, hb, z, znb);

    // ---- set transformer: light MFMA kernels, B direct from pre-converted bf16 tables ----
    dim3 gqkv((NG+63)/64, 1, 3);
    k_qkv_g<<<gqkv, 256, 0, stream>>>(znb, Wqb, Wkb, Wvb, bq, bk, bv, qb, kb2, vb);
    k_attn<<<NS*4, 256, 0, stream>>>(qb, kb2, vb, ao);
    k_wo_ln<<<(NG+31)/32, 256, 0, stream>>>(ao, Wo, bo, z, ln1_g, ln1_b, zd1, zd1b);
    dim3 gffn1((NG+63)/64, FFN_DIM/128);
    k_ffn1_g<<<gffn1, 256, 0, stream>>>(zd1b, W1b, b1, ffn1b);
    dim3 gffn2((NG+63)/64, 1, KSPLIT);
    k_ffn2_g<<<gffn2, 256, 0, stream>>>(ffn1b, W2b, part);
    k_ln_red_gsi<<<NG/4, 256, 0, stream>>>(zd1, part, b2, ln2_g, ln2_b,
                                           Wg + (size_t)F*F, bg, zd2, gsi);

    // ---- gated fusion -> output ----
    k_gate_mfma<<<(NN+63)/64, 256, 0, stream>>>(h, hb, Wgb, gsi, zd2, out);
}